// Round 18
// baseline (1531.070 us; speedup 1.0000x reference)
//
#include <hip/hip_runtime.h>
#include <stdint.h>

typedef __attribute__((ext_vector_type(8))) short bf16x8;
typedef __attribute__((ext_vector_type(4))) short bf16x4;
typedef __attribute__((ext_vector_type(4))) float f32x4;
typedef __attribute__((ext_vector_type(2))) unsigned int u32x2;

#define NSCALE 0.17677669529663687f

static __device__ __forceinline__ float bf2f(unsigned short h) {
  union { unsigned int u; float f; } c; c.u = ((unsigned int)h) << 16; return c.f;
}
static __device__ __forceinline__ unsigned short f2bf(float f) {
  union { float f; unsigned int u; } c; c.f = f;
  unsigned int u = c.u;
  u = (u + 0x7FFFu + ((u >> 16) & 1u)) >> 16;
  return (unsigned short)u;
}
static __device__ __forceinline__ unsigned int cvtpk(float a, float b) {
  unsigned int r;
  asm("v_cvt_pk_bf16_f32 %0, %1, %2" : "=v"(r) : "v"(a), "v"(b));
  return r;
}

// ---------------- ws layout (bf16 elements) ----------------
#define W_QKVW  0                     // [1152][384], q-rows pre-scaled
#define W_PROJW 442368                // [384][384]
#define W_BIASE 589824                // [12][49][50]
#define W_MASKE 619224                // [64][49][50]
#define W_ELEMS 776024
#define W_BYTES (W_ELEMS * 2)         // 1.55 MB

__global__ void cvt_w_kernel(const float* __restrict__ qkv_w,
                             const float* __restrict__ proj_w,
                             unsigned short* __restrict__ ws) {
  const int i = blockIdx.x * 256 + threadIdx.x;
  const int stride = gridDim.x * 256;
  for (int e = i; e < 442368; e += stride)
    ws[W_QKVW + e] = f2bf(qkv_w[e] * (e < 147456 ? NSCALE : 1.f));
  for (int e = i; e < 147456; e += stride)
    ws[W_PROJW + e] = f2bf(proj_w[e]);
}

__global__ void biase_kernel(const float* __restrict__ bias_t,
                             unsigned short* __restrict__ ws) {
  const int h = blockIdx.x;
  unsigned short* dst = ws + W_BIASE + h * 2450;
  for (int e = threadIdx.x; e < 2401; e += 256) {
    const int q = e / 49, k = e - q * 49;
    const int i1 = q / 7, j1 = q - i1 * 7;
    const int i2 = k / 7, j2 = k - i2 * 7;
    const int ridx = (i1 - i2 + 6) * 13 + (j1 - j2 + 6);
    dst[q * 50 + k] = f2bf(bias_t[ridx * 12 + h]);
  }
}

__global__ void maske_kernel(const float* __restrict__ mask,
                             unsigned short* __restrict__ ws) {
  const int wn = blockIdx.x;
  const float* mw = mask + wn * 2401;
  unsigned short* dst = ws + W_MASKE + wn * 2450;
  for (int e = threadIdx.x; e < 2401; e += 256) {
    const int q = e / 49, k = e - q * 49;
    dst[q * 50 + k] = f2bf(mw[e]);
  }
}

// ============ Kernel A: wave-private qkv+attn, ZERO barriers ============
// Each wave owns heads {w, w+4, w+8}; Q/K/V in private LDS slice; A-fragments
// read from global f32 x (L2-hot); O written bf16 into out[b]'s own slot.
#define A_BUF 6224                    // Q[49][40] | K[49][40] | V[32][72]
#define A_LDS_EL (4 * A_BUF)          // 24896 ush
#define A_LDS_BYTES (A_LDS_EL * 2)    // 49,792 B -> 3 blocks/CU by LDS

__global__ void __launch_bounds__(256)
__attribute__((amdgpu_waves_per_eu(2, 4)))
wa18_qkv_attn(const float* __restrict__ x,
              const float* __restrict__ qkv_b,
              const unsigned short* __restrict__ ws,
              unsigned short* __restrict__ og)
{
  extern __shared__ unsigned short sm[];
  const int b = blockIdx.x;
  const int tid = threadIdx.x;
  const int w = tid >> 6, lane = tid & 63, l15 = lane & 15, lg = lane >> 4;

  unsigned short* Qb = sm + w * A_BUF;
  unsigned short* Kb = Qb + 1960;
  unsigned short* Vb = Qb + 3920;

  const unsigned short* wsQW = ws + W_QKVW;
  const unsigned short* wsBE = ws + W_BIASE;
  const unsigned short* wsME = ws + W_MASKE;
  const float* xb = x + (size_t)b * 18816;
  unsigned short* ob16 = og + (size_t)b * 37632;   // O[b] inside out[b] slot
  const unsigned short* meb = wsME + (b & 63) * 2450;

#pragma unroll
  for (int hi = 0; hi < 3; ++hi) {
    const int head = w + 4 * hi;                   // wave-private head

    // -------- GEMM1 for this head: 2 passes x (3 n-tiles x 4 m-tiles) --------
#pragma unroll
    for (int pp = 0; pp < 2; ++pp) {
      const unsigned short* bp[3];
      float bias[3];
      int ss[3], hf_[3];
#pragma unroll
      for (int i = 0; i < 3; ++i) {
        const int nt = 3 * pp + i;                 // 0..5 = q0,q1,k0,k1,v0,v1
        const int s = nt >> 1, hf = nt & 1;
        const int o = s * 384 + head * 32 + hf * 16 + l15;
        bp[i] = wsQW + o * 384 + lg * 8;
        bias[i] = qkv_b[o] * (s == 0 ? NSCALE : 1.f);
        ss[i] = s; hf_[i] = hf;
      }
      f32x4 acc[3][4];
#pragma unroll
      for (int i = 0; i < 3; ++i)
#pragma unroll
        for (int mi = 0; mi < 4; ++mi) acc[i][mi] = (f32x4){0.f, 0.f, 0.f, 0.f};
#pragma unroll
      for (int kk = 0; kk < 12; ++kk) {
        bf16x8 A4[4];
#pragma unroll
        for (int mi = 0; mi < 4; ++mi) {
          const int ar0 = mi * 16 + l15;
          const int ar = ar0 > 48 ? 48 : ar0;
          const float* ap = xb + ar * 384 + kk * 32 + lg * 8;
          f32x4 v0 = *(const f32x4*)ap;
          f32x4 v1 = *(const f32x4*)(ap + 4);
          union { bf16x8 v; unsigned int u[4]; } cv;
          cv.u[0] = cvtpk(v0[0], v0[1]);
          cv.u[1] = cvtpk(v0[2], v0[3]);
          cv.u[2] = cvtpk(v1[0], v1[1]);
          cv.u[3] = cvtpk(v1[2], v1[3]);
          A4[mi] = cv.v;
        }
        bf16x8 B3[3];
#pragma unroll
        for (int i = 0; i < 3; ++i) B3[i] = *(const bf16x8*)(bp[i] + kk * 32);
#pragma unroll
        for (int i = 0; i < 3; ++i)
#pragma unroll
          for (int mi = 0; mi < 4; ++mi)
            acc[i][mi] = __builtin_amdgcn_mfma_f32_16x16x32_bf16(A4[mi], B3[i], acc[i][mi], 0, 0, 0);
      }
      // stores into wave-private LDS (R14-verified addressing)
#pragma unroll
      for (int i = 0; i < 3; ++i) {
        const int s = ss[i], hf = hf_[i];
        if (s < 2) {
          unsigned short* T = (s == 0 ? Qb : Kb) + hf * 16 + l15;
#pragma unroll
          for (int mi = 0; mi < 4; ++mi) {
            const int r0 = mi * 16 + lg * 4;
            const unsigned int pk01 = cvtpk(acc[i][mi][0] + bias[i], acc[i][mi][1] + bias[i]);
            const unsigned int pk23 = cvtpk(acc[i][mi][2] + bias[i], acc[i][mi][3] + bias[i]);
            if (r0 < 49)     T[r0 * 40]       = (unsigned short)pk01;
            if (r0 + 1 < 49) T[(r0 + 1) * 40] = (unsigned short)(pk01 >> 16);
            if (r0 + 2 < 49) T[(r0 + 2) * 40] = (unsigned short)pk23;
            if (r0 + 3 < 49) T[(r0 + 3) * 40] = (unsigned short)(pk23 >> 16);
          }
        } else {
#pragma unroll
          for (int mi = 0; mi < 4; ++mi) {
            u32x2 pk;
            pk[0] = cvtpk(acc[i][mi][0] + bias[i], acc[i][mi][1] + bias[i]);
            pk[1] = cvtpk(acc[i][mi][2] + bias[i], acc[i][mi][3] + bias[i]);
            *(u32x2*)(Vb + (hf * 16 + l15) * 72 + mi * 16 + lg * 4) = pk;
          }
        }
      }
    }
    // no barrier: same wave wrote, same wave reads (lgkmcnt auto-inserted)

    // -------- attn for this head: 4 q-tiles (R14-verified body) --------
#pragma unroll
    for (int qt = 0; qt < 4; ++qt) {
      const int q = qt * 16 + l15;
      const int qc = q > 48 ? 48 : q;
      bf16x8 Qf = *(const bf16x8*)(Qb + qc * 40 + lg * 8);
      f32x4 S[4];
#pragma unroll
      for (int mt = 0; mt < 4; ++mt) {
        const int kr = mt * 16 + l15;
        bf16x8 Kf = *(const bf16x8*)(Kb + (kr > 48 ? 48 : kr) * 40 + lg * 8);
        f32x4 z = {0.f, 0.f, 0.f, 0.f};
        S[mt] = __builtin_amdgcn_mfma_f32_16x16x32_bf16(Kf, Qf, z, 0, 0, 0);
      }
      const unsigned short* be = wsBE + head * 2450 + qc * 50;
      const unsigned short* ms = meb + qc * 50;
      float p[16];
      float vmax = -3e30f;
#pragma unroll
      for (int mt = 0; mt < 4; ++mt) {
        const int kc0 = mt * 16 + lg * 4;
        const int ko = kc0 > 48 ? 48 : kc0;
        const unsigned int b01 = *(const unsigned int*)(be + ko);
        const unsigned int b23 = *(const unsigned int*)(be + ko + 2);
        const unsigned int m01 = *(const unsigned int*)(ms + ko);
        const unsigned int m23 = *(const unsigned int*)(ms + ko + 2);
        float ad0 = bf2f((unsigned short)(b01 & 0xffff)) + bf2f((unsigned short)(m01 & 0xffff));
        float ad1 = bf2f((unsigned short)(b01 >> 16))    + bf2f((unsigned short)(m01 >> 16));
        float ad2 = bf2f((unsigned short)(b23 & 0xffff)) + bf2f((unsigned short)(m23 & 0xffff));
        float ad3 = bf2f((unsigned short)(b23 >> 16))    + bf2f((unsigned short)(m23 >> 16));
        float v0 = S[mt][0] + ad0, v1 = S[mt][1] + ad1;
        float v2 = S[mt][2] + ad2, v3 = S[mt][3] + ad3;
        if (kc0 + 0 >= 49) v0 = -3e30f;
        if (kc0 + 1 >= 49) v1 = -3e30f;
        if (kc0 + 2 >= 49) v2 = -3e30f;
        if (kc0 + 3 >= 49) v3 = -3e30f;
        p[mt * 4 + 0] = v0; p[mt * 4 + 1] = v1;
        p[mt * 4 + 2] = v2; p[mt * 4 + 3] = v3;
        vmax = fmaxf(fmaxf(fmaxf(v0, v1), fmaxf(v2, v3)), vmax);
      }
      vmax = fmaxf(vmax, __shfl_xor(vmax, 16, 64));
      vmax = fmaxf(vmax, __shfl_xor(vmax, 32, 64));
      float ssum = 0.f;
#pragma unroll
      for (int i = 0; i < 16; ++i) { p[i] = __expf(p[i] - vmax); ssum += p[i]; }
      ssum += __shfl_xor(ssum, 16, 64);
      ssum += __shfl_xor(ssum, 32, 64);
      const float rs = 1.f / ssum;
      unsigned int plo[4], phi[4];
#pragma unroll
      for (int mt = 0; mt < 4; ++mt) {
        plo[mt] = cvtpk(p[mt * 4 + 0], p[mt * 4 + 1]);
        phi[mt] = cvtpk(p[mt * 4 + 2], p[mt * 4 + 3]);
      }
      union { bf16x8 v; unsigned int u[4]; } PB[2];
      const int src0 = l15 + ((lg & 1) << 5);
      const int src1 = src0 + 16;
      const int sel = lg >> 1;
#pragma unroll
      for (int ks = 0; ks < 2; ++ks) {
        const int a0 = __shfl((int)plo[2 * ks], src0, 64), a1 = __shfl((int)plo[2 * ks + 1], src0, 64);
        const int b0 = __shfl((int)phi[2 * ks], src0, 64), b1 = __shfl((int)phi[2 * ks + 1], src0, 64);
        const int c0 = __shfl((int)plo[2 * ks], src1, 64), c1 = __shfl((int)plo[2 * ks + 1], src1, 64);
        const int d0 = __shfl((int)phi[2 * ks], src1, 64), d1 = __shfl((int)phi[2 * ks + 1], src1, 64);
        PB[ks].u[0] = (unsigned)(sel ? a1 : a0);
        PB[ks].u[1] = (unsigned)(sel ? b1 : b0);
        PB[ks].u[2] = (unsigned)(sel ? c1 : c0);
        PB[ks].u[3] = (unsigned)(sel ? d1 : d0);
      }
#pragma unroll
      for (int dt = 0; dt < 2; ++dt) {
        f32x4 a = {0.f, 0.f, 0.f, 0.f};
#pragma unroll
        for (int ks = 0; ks < 2; ++ks) {
          bf16x8 Vf = *(const bf16x8*)(Vb + (dt * 16 + l15) * 72 + ks * 32 + lg * 8);
          a = __builtin_amdgcn_mfma_f32_16x16x32_bf16(Vf, PB[ks].v, a, 0, 0, 0);
        }
        if (q < 49) {
          u32x2 pk;
          pk[0] = cvtpk(a[0] * rs, a[1] * rs);
          pk[1] = cvtpk(a[2] * rs, a[3] * rs);
          *(u32x2*)(ob16 + q * 384 + head * 32 + dt * 16 + lg * 4) = pk;
        }
      }
    }
  }
}

// ============ Kernel B: projection (R13-verified) ============
#define B_LDS_EL 19208
#define B_LDS_BYTES (B_LDS_EL * 2)    // 38,416 B -> 4 blocks/CU

__global__ void __launch_bounds__(256)
__attribute__((amdgpu_waves_per_eu(2, 4)))
wa18_proj(float* __restrict__ out,
          const float* __restrict__ proj_b,
          const unsigned short* __restrict__ ws)
{
  extern __shared__ unsigned short sm[];
  unsigned short* Osl = sm;

  const unsigned short* wsPW = ws + W_PROJW;
  const int b = blockIdx.x;
  const int tid = threadIdx.x;
  const int w = tid >> 6, lane = tid & 63, l15 = lane & 15, lg = lane >> 4;

  const unsigned short* og = (const unsigned short*)out + (size_t)b * 37632;
  for (int e = tid; e < 2352; e += 256) {
    const int f = e << 3;
    const int r = f / 384;
    const int c = f - r * 384;
    *(bf16x8*)(Osl + r * 392 + c) = *(const bf16x8*)(og + f);
  }
  __syncthreads();

  float* ob = out + (size_t)b * 18816;
#pragma unroll
  for (int pp = 0; pp < 2; ++pp) {
    const unsigned short* bp[3];
    float pb[3];
    int co[3];
#pragma unroll
    for (int i = 0; i < 3; ++i) {
      co[i] = (6 * w + 3 * pp + i) * 16 + l15;
      bp[i] = wsPW + co[i] * 384 + lg * 8;
      pb[i] = proj_b[co[i]];
    }
    f32x4 acc[3][4];
#pragma unroll
    for (int i = 0; i < 3; ++i)
#pragma unroll
      for (int mi = 0; mi < 4; ++mi) acc[i][mi] = (f32x4){0.f, 0.f, 0.f, 0.f};
#pragma unroll
    for (int kk = 0; kk < 12; ++kk) {
      bf16x8 A4[4];
#pragma unroll
      for (int mi = 0; mi < 4; ++mi) {
        const int ar = mi * 16 + l15;
        A4[mi] = *(const bf16x8*)(Osl + (ar > 48 ? 48 : ar) * 392 + kk * 32 + lg * 8);
      }
      bf16x8 B3[3];
#pragma unroll
      for (int i = 0; i < 3; ++i) B3[i] = *(const bf16x8*)(bp[i] + kk * 32);
#pragma unroll
      for (int i = 0; i < 3; ++i)
#pragma unroll
        for (int mi = 0; mi < 4; ++mi)
          acc[i][mi] = __builtin_amdgcn_mfma_f32_16x16x32_bf16(A4[mi], B3[i], acc[i][mi], 0, 0, 0);
    }
#pragma unroll
    for (int i = 0; i < 3; ++i)
#pragma unroll
      for (int mi = 0; mi < 4; ++mi)
#pragma unroll
        for (int j = 0; j < 4; ++j) {
          const int row = mi * 16 + lg * 4 + j;
          if (row < 49) ob[row * 384 + co[i]] = acc[i][mi][j] + pb[i];
        }
  }
}

// ---------------- fallback (round-2 monolith, f32-direct, known-good) ----------------
#define FXS 0
#define FQS (FXS + 64*392)
#define FKS (FQS + 2*64*40)
#define FVT (FKS + 2*64*40)
#define FPS (FVT + 2*32*72)
#define FOS (FPS + 2*64*72)
#define FMS (FOS + 64*392)
#define FBS (FMS + 2408)
#define FLDS_EL (FBS + 2028)
#define FLDS_BYTES (FLDS_EL * 2)

static __device__ __forceinline__ bf16x8 cvt8(const float* p) {
  f32x4 a = *(const f32x4*)p;
  f32x4 b = *(const f32x4*)(p + 4);
  bf16x8 r;
  r[0]=(short)f2bf(a[0]); r[1]=(short)f2bf(a[1]); r[2]=(short)f2bf(a[2]); r[3]=(short)f2bf(a[3]);
  r[4]=(short)f2bf(b[0]); r[5]=(short)f2bf(b[1]); r[6]=(short)f2bf(b[2]); r[7]=(short)f2bf(b[3]);
  return r;
}

__global__ __launch_bounds__(512, 2)
void winattn_fb(const float* __restrict__ x, const float* __restrict__ mask,
                const float* __restrict__ bias_t, const float* __restrict__ qkv_w,
                const float* __restrict__ qkv_b, const float* __restrict__ proj_w,
                const float* __restrict__ proj_b, float* __restrict__ out)
{
  extern __shared__ unsigned short sm[];
  unsigned short* Xs = sm + FXS; unsigned short* Qs = sm + FQS;
  unsigned short* Ks = sm + FKS; unsigned short* Vt = sm + FVT;
  unsigned short* Ps = sm + FPS; unsigned short* Os = sm + FOS;
  unsigned short* Ms = sm + FMS; unsigned short* Bs = sm + FBS;
  const int b = blockIdx.x, tid = threadIdx.x;
  const int w = tid >> 6, lane = tid & 63, l15 = lane & 15, lg = lane >> 4;
  const float* xw = x + b * 18816;
  for (int e = tid; e < 4704; e += 512) {
    const int f = e << 2; const int r = f / 384; const int c = f - r * 384;
    f32x4 v = *(const f32x4*)(xw + f);
    unsigned short* dst = Xs + r * 392 + c;
    dst[0]=f2bf(v[0]); dst[1]=f2bf(v[1]); dst[2]=f2bf(v[2]); dst[3]=f2bf(v[3]);
  }
  { bf16x8 z = {0,0,0,0,0,0,0,0};
    for (int e = tid; e < 735; e += 512) *(bf16x8*)(Xs + 19208 + (e << 3)) = z; }
  { const float* mw = mask + (b & 63) * 2401;
    for (int e = tid; e < 2401; e += 512) Ms[e] = f2bf(mw[e]);
    for (int e = tid; e < 2028; e += 512) Bs[e] = f2bf(bias_t[e]); }
  __syncthreads();
  for (int g = 0; g < 6; ++g) {
    int t = 6 * w; const int tEnd = t + 6;
    while (t < tEnd) {
      const int nt = t >> 2; const int hh = nt / 6; const int ntl = nt - hh * 6;
      const int s = ntl >> 1; const int dd = ((nt & 1) << 4) + l15;
      const int o = s * 384 + (2 * g + hh) * 32 + dd;
      bf16x8 Bf[12];
      const float* wp = qkv_w + o * 384 + lg * 8;
#pragma unroll
      for (int kk = 0; kk < 12; ++kk) Bf[kk] = cvt8(wp + kk * 32);
      const float biasc = qkv_b[o];
      for (; t < tEnd && (t >> 2) == nt; ++t) {
        const int mt = t & 3;
        f32x4 acc = {0.f,0.f,0.f,0.f};
        const unsigned short* ap = Xs + (mt * 16 + l15) * 392 + lg * 8;
#pragma unroll
        for (int kk = 0; kk < 12; ++kk) {
          bf16x8 Af = *(const bf16x8*)(ap + kk * 32);
          acc = __builtin_amdgcn_mfma_f32_16x16x32_bf16(Af, Bf[kk], acc, 0,0,0);
        }
#pragma unroll
        for (int j = 0; j < 4; ++j) {
          const int row = mt * 16 + lg * 4 + j;
          const unsigned short hv = f2bf(acc[j] + biasc);
          if (s == 0) Qs[hh * 2560 + row * 40 + dd] = hv;
          else if (s == 1) Ks[hh * 2560 + row * 40 + dd] = hv;
          else Vt[hh * 2304 + dd * 72 + row] = hv;
        }
      }
    }
    __syncthreads();
    {
      const int hh = w >> 2; const int mt = w & 3; const int head = 2 * g + hh;
      bf16x8 Aq = *(const bf16x8*)(Qs + hh * 2560 + (mt * 16 + l15) * 40 + lg * 8);
      f32x4 accs[4];
#pragma unroll
      for (int nt = 0; nt < 4; ++nt) {
        bf16x8 Bk = *(const bf16x8*)(Ks + hh * 2560 + (nt * 16 + l15) * 40 + lg * 8);
        f32x4 z = {0.f,0.f,0.f,0.f};
        accs[nt] = __builtin_amdgcn_mfma_f32_16x16x32_bf16(Aq, Bk, z, 0,0,0);
      }
#pragma unroll
      for (int j = 0; j < 4; ++j) {
        const int row = mt * 16 + lg * 4 + j;
        float sv[4]; float vmax = -3e30f;
#pragma unroll
        for (int nt = 0; nt < 4; ++nt) {
          const int col = nt * 16 + l15;
          float v = accs[nt][j] * NSCALE;
          if (col < 49) { if (row < 49) {
              const int i1 = row / 7, j1 = row - i1 * 7;
              const int i2 = col / 7, j2 = col - i2 * 7;
              const int ridx = (i1 - i2 + 6) * 13 + (j1 - j2 + 6);
              v += bf2f(Ms[row * 49 + col]) + bf2f(Bs[ridx * 12 + head]); } }
          else v = -3e30f;
          sv[nt] = v; vmax = fmaxf(vmax, v);
        }
#pragma unroll
        for (int mm = 1; mm < 16; mm <<= 1) vmax = fmaxf(vmax, __shfl_xor(vmax, mm, 64));
        float ssum = 0.f;
#pragma unroll
        for (int nt = 0; nt < 4; ++nt) { sv[nt] = __expf(sv[nt] - vmax); ssum += sv[nt]; }
#pragma unroll
        for (int mm = 1; mm < 16; mm <<= 1) ssum += __shfl_xor(ssum, mm, 64);
        const float rs = 1.f / ssum;
#pragma unroll
        for (int nt = 0; nt < 4; ++nt)
          Ps[hh * 4608 + row * 72 + nt * 16 + l15] = f2bf(sv[nt] * rs);
      }
    }
    __syncthreads();
    {
      const int hh = w >> 2; const int mt = w & 3; const int head = 2 * g + hh;
#pragma unroll
      for (int nt = 0; nt < 2; ++nt) {
        f32x4 acc = {0.f,0.f,0.f,0.f};
#pragma unroll
        for (int kk = 0; kk < 2; ++kk) {
          bf16x8 Ap = *(const bf16x8*)(Ps + hh * 4608 + (mt * 16 + l15) * 72 + kk * 32 + lg * 8);
          bf16x8 Bv = *(const bf16x8*)(Vt + hh * 2304 + (nt * 16 + l15) * 72 + kk * 32 + lg * 8);
          acc = __builtin_amdgcn_mfma_f32_16x16x32_bf16(Ap, Bv, acc, 0,0,0);
        }
#pragma unroll
        for (int j = 0; j < 4; ++j)
          Os[(mt * 16 + lg * 4 + j) * 392 + head * 32 + nt * 16 + l15] = f2bf(acc[j]);
      }
    }
    __syncthreads();
  }
  for (int nt = 3 * w; nt < 3 * w + 3; ++nt) {
    const int co = nt * 16 + l15;
    bf16x8 Bf[12];
    const float* wp = proj_w + co * 384 + lg * 8;
#pragma unroll
    for (int kk = 0; kk < 12; ++kk) Bf[kk] = cvt8(wp + kk * 32);
    const float pb = proj_b[co];
#pragma unroll
    for (int mt = 0; mt < 4; ++mt) {
      f32x4 acc = {0.f,0.f,0.f,0.f};
      const unsigned short* ap = Os + (mt * 16 + l15) * 392 + lg * 8;
#pragma unroll
      for (int kk = 0; kk < 12; ++kk) {
        bf16x8 Af = *(const bf16x8*)(ap + kk * 32);
        acc = __builtin_amdgcn_mfma_f32_16x16x32_bf16(Af, Bf[kk], acc, 0,0,0);
      }
#pragma unroll
      for (int j = 0; j < 4; ++j) {
        const int row = mt * 16 + lg * 4 + j;
        if (row < 49) out[b * 18816 + row * 384 + co] = acc[j] + pb;
      }
    }
  }
}

extern "C" void kernel_launch(void* const* d_in, const int* in_sizes, int n_in,
                              void* d_out, int out_size, void* d_ws, size_t ws_size,
                              hipStream_t stream) {
  const float* x      = (const float*)d_in[0];
  const float* mask   = (const float*)d_in[1];
  const float* bias_t = (const float*)d_in[2];
  const float* qkv_w  = (const float*)d_in[3];
  const float* qkv_b  = (const float*)d_in[4];
  const float* proj_w = (const float*)d_in[5];
  const float* proj_b = (const float*)d_in[6];
  float* out = (float*)d_out;

  if (ws_size >= (size_t)W_BYTES) {
    unsigned short* ws = (unsigned short*)d_ws;
    cvt_w_kernel<<<dim3(1024), dim3(256), 0, stream>>>(qkv_w, proj_w, ws);
    biase_kernel<<<dim3(12), dim3(256), 0, stream>>>(bias_t, ws);
    maske_kernel<<<dim3(64), dim3(256), 0, stream>>>(mask, ws);
    (void)hipFuncSetAttribute((const void*)wa18_qkv_attn,
                              hipFuncAttributeMaxDynamicSharedMemorySize, A_LDS_BYTES);
    wa18_qkv_attn<<<dim3(4096), dim3(256), A_LDS_BYTES, stream>>>(
        x, qkv_b, ws, (unsigned short*)d_out);
    (void)hipFuncSetAttribute((const void*)wa18_proj,
                              hipFuncAttributeMaxDynamicSharedMemorySize, B_LDS_BYTES);
    wa18_proj<<<dim3(4096), dim3(256), B_LDS_BYTES, stream>>>(
        out, proj_b, ws);
  } else {
    (void)hipFuncSetAttribute((const void*)winattn_fb,
                              hipFuncAttributeMaxDynamicSharedMemorySize, FLDS_BYTES);
    winattn_fb<<<dim3(4096), dim3(512), FLDS_BYTES, stream>>>(
        x, mask, bias_t, qkv_w, qkv_b, proj_w, proj_b, out);
  }
}

// Round 19
// 746.383 us; speedup vs baseline: 2.0513x; 2.0513x over previous
//
#include <hip/hip_runtime.h>
#include <stdint.h>

typedef __attribute__((ext_vector_type(8))) short bf16x8;
typedef __attribute__((ext_vector_type(4))) short bf16x4;
typedef __attribute__((ext_vector_type(4))) float f32x4;
typedef __attribute__((ext_vector_type(2))) unsigned int u32x2;

#define NSCALE 0.17677669529663687f

static __device__ __forceinline__ float bf2f(unsigned short h) {
  union { unsigned int u; float f; } c; c.u = ((unsigned int)h) << 16; return c.f;
}
// manual RNE (pre-pass kernels only)
static __device__ __forceinline__ unsigned short f2bf(float f) {
  union { float f; unsigned int u; } c; c.f = f;
  unsigned int u = c.u;
  u = (u + 0x7FFFu + ((u >> 16) & 1u)) >> 16;
  return (unsigned short)u;
}
// HW packed convert: D[15:0]=bf16(a), D[31:16]=bf16(b), RNE (gfx950)
static __device__ __forceinline__ unsigned int cvtpk(float a, float b) {
  unsigned int r;
  asm("v_cvt_pk_bf16_f32 %0, %1, %2" : "=v"(r) : "v"(a), "v"(b));
  return r;
}

// ---------------- ws layout (bf16 elements) ----------------
#define W_QKVW  0                     // [1152][384], q-rows (0..383) pre-scaled
#define W_PROJW 442368                // [384][384]
#define W_BIASE 589824                // [12][49][50] bias pre-expanded
#define W_ELEMS 619240
#define W_BYTES (W_ELEMS * 2)         // 1.24 MB

__global__ void cvt_w_kernel(const float* __restrict__ qkv_w,
                             const float* __restrict__ proj_w,
                             unsigned short* __restrict__ ws) {
  const int i = blockIdx.x * 256 + threadIdx.x;
  const int stride = gridDim.x * 256;
  for (int e = i; e < 442368; e += stride)
    ws[W_QKVW + e] = f2bf(qkv_w[e] * (e < 147456 ? NSCALE : 1.f));
  for (int e = i; e < 147456; e += stride)
    ws[W_PROJW + e] = f2bf(proj_w[e]);
}

__global__ void biase_kernel(const float* __restrict__ bias_t,
                             unsigned short* __restrict__ ws) {
  const int h = blockIdx.x;                    // 0..11
  unsigned short* dst = ws + W_BIASE + h * 2450;
  for (int e = threadIdx.x; e < 2401; e += 256) {
    const int q = e / 49, k = e - q * 49;
    const int i1 = q / 7, j1 = q - i1 * 7;
    const int i2 = k / 7, j2 = k - i2 * 7;
    const int ridx = (i1 - i2 + 6) * 13 + (j1 - j2 + 6);
    dst[q * 50 + k] = f2bf(bias_t[ridx * 12 + h]);
  }
}

// ---------------- LDS layout (ush offsets), 256-thread / 4-wave block ----------
#define XS_O  0
#define U_O   19208
#define QS_O  (U_O)
#define KS_O  (U_O + 3920)
#define VT_O  (U_O + 7840)
#define MSP_O (U_O + 12448)
#define LDS_EL (U_O + 12448 + 2458)   // 34114 ush
#define LDS_BYTES2 (LDS_EL * 2)       // 68228 B -> 2 blocks/CU by LDS

__global__ void __launch_bounds__(256)
__attribute__((amdgpu_waves_per_eu(2, 4)))
winattn14(const float* __restrict__ x,
          const float* __restrict__ mask,
          const float* __restrict__ qkv_b,
          const float* __restrict__ proj_b,
          const unsigned short* __restrict__ ws,
          float* __restrict__ out)
{
  extern __shared__ unsigned short sm[];
  unsigned short* Xs  = sm + XS_O;
  unsigned short* Qs  = sm + QS_O;
  unsigned short* Ks  = sm + KS_O;
  unsigned short* Vt  = sm + VT_O;
  unsigned short* Msp = sm + MSP_O;
  unsigned short* Os  = sm + XS_O;    // alias over dead Xs

  const unsigned short* wsQW = ws + W_QKVW;
  const unsigned short* wsPW = ws + W_PROJW;
  const unsigned short* wsBE = ws + W_BIASE;

  const int b = blockIdx.x;
  const int tid = threadIdx.x;
  const int w = tid >> 6, lane = tid & 63, l15 = lane & 15, lg = lane >> 4;

  // -------- phase 0: stage X (f32->bf16 via cvt_pk) and padded mask --------
  const float* xw = x + b * 18816;
  for (int e = tid; e < 4704; e += 256) {
    const int f = e << 2;
    const int r = f / 384;
    const int c = f - r * 384;
    f32x4 v = *(const f32x4*)(xw + f);
    u32x2 pk; pk[0] = cvtpk(v[0], v[1]); pk[1] = cvtpk(v[2], v[3]);
    *(u32x2*)(Xs + r * 392 + c) = pk;
  }
  {
    const float* mw = mask + (b & 63) * 2401;
    for (int e = tid; e < 2401; e += 256) {
      const int q = e / 49, k = e - q * 49;
      Msp[q * 50 + k] = (unsigned short)cvtpk(mw[e], mw[e]);
    }
  }
  __syncthreads();

  // attn per-lane constants (wave w owns q-tile w)
  const int q  = w * 16 + l15;
  const int qc = q > 48 ? 48 : q;

  unsigned int opk[6][2][2][2];                 // [g][hh][dt][pk] static idx only

  for (int g = 0; g < 6; ++g) {
    const int hb = 2 * g;
    // -------- GEMM1: (3 n-tiles x 4 m-tiles) register block, A reused 3x --------
    {
      const int ntb = 3 * w;
      const unsigned short* bp[3];
      float bias[3];
#pragma unroll
      for (int i = 0; i < 3; ++i) {
        const int nt = ntb + i;
        const int s = nt >> 2, sub = nt & 3, hh = sub >> 1, hf = sub & 1;
        const int o = s * 384 + (hb + hh) * 32 + hf * 16 + l15;
        bp[i] = wsQW + o * 384 + lg * 8;
        bias[i] = qkv_b[o] * (s == 0 ? NSCALE : 1.f);
      }
      f32x4 acc[3][4];
#pragma unroll
      for (int i = 0; i < 3; ++i)
#pragma unroll
        for (int mi = 0; mi < 4; ++mi) acc[i][mi] = (f32x4){0.f, 0.f, 0.f, 0.f};
#pragma unroll
      for (int kk = 0; kk < 12; ++kk) {
        bf16x8 A4[4];
#pragma unroll
        for (int mi = 0; mi < 4; ++mi) {
          const int ar = mi * 16 + l15;
          A4[mi] = *(const bf16x8*)(Xs + (ar > 48 ? 48 : ar) * 392 + kk * 32 + lg * 8);
        }
        bf16x8 B3[3];
#pragma unroll
        for (int i = 0; i < 3; ++i) B3[i] = *(const bf16x8*)(bp[i] + kk * 32);
#pragma unroll
        for (int i = 0; i < 3; ++i)
#pragma unroll
          for (int mi = 0; mi < 4; ++mi)
            acc[i][mi] = __builtin_amdgcn_mfma_f32_16x16x32_bf16(A4[mi], B3[i], acc[i][mi], 0, 0, 0);
      }
      // stores (same addressing as verified R8/R11; cvt_pk packing)
#pragma unroll
      for (int i = 0; i < 3; ++i) {
        const int nt = ntb + i;
        const int s = nt >> 2, sub = nt & 3, hh = sub >> 1, hf = sub & 1;
        if (s < 2) {
          unsigned short* T = (s == 0 ? Qs : Ks) + hh * 1960 + hf * 16 + l15;
#pragma unroll
          for (int mi = 0; mi < 4; ++mi) {
            const int r0 = mi * 16 + lg * 4;
            const unsigned int pk01 = cvtpk(acc[i][mi][0] + bias[i], acc[i][mi][1] + bias[i]);
            const unsigned int pk23 = cvtpk(acc[i][mi][2] + bias[i], acc[i][mi][3] + bias[i]);
            if (r0 < 49)     T[r0 * 40]       = (unsigned short)pk01;
            if (r0 + 1 < 49) T[(r0 + 1) * 40] = (unsigned short)(pk01 >> 16);
            if (r0 + 2 < 49) T[(r0 + 2) * 40] = (unsigned short)pk23;
            if (r0 + 3 < 49) T[(r0 + 3) * 40] = (unsigned short)(pk23 >> 16);
          }
        } else {
#pragma unroll
          for (int mi = 0; mi < 4; ++mi) {
            u32x2 pk;
            pk[0] = cvtpk(acc[i][mi][0] + bias[i], acc[i][mi][1] + bias[i]);
            pk[1] = cvtpk(acc[i][mi][2] + bias[i], acc[i][mi][3] + bias[i]);
            *(u32x2*)(Vt + hh * 2304 + (hf * 16 + l15) * 72 + mi * 16 + lg * 4) = pk;
          }
        }
      }
    }
    __syncthreads();

    // -------- attn: wave = q-tile w, both heads sequentially (verified R8/R11) ----
#pragma unroll
    for (int hh = 0; hh < 2; ++hh) {
      const int head = hb + hh;
      bf16x8 Qf = *(const bf16x8*)(Qs + hh * 1960 + qc * 40 + lg * 8);
      f32x4 S[4];
#pragma unroll
      for (int mt = 0; mt < 4; ++mt) {
        const int kr = mt * 16 + l15;
        bf16x8 Kf = *(const bf16x8*)(Ks + hh * 1960 + (kr > 48 ? 48 : kr) * 40 + lg * 8);
        f32x4 z = {0.f, 0.f, 0.f, 0.f};
        S[mt] = __builtin_amdgcn_mfma_f32_16x16x32_bf16(Kf, Qf, z, 0, 0, 0);
      }
      const unsigned short* be = wsBE + head * 2450 + qc * 50;
      const unsigned short* ms = Msp + qc * 50;
      float p[16];
      float vmax = -3e30f;
#pragma unroll
      for (int mt = 0; mt < 4; ++mt) {
        const int kc0 = mt * 16 + lg * 4;
        const int ko = kc0 > 48 ? 48 : kc0;
        const unsigned int b01 = *(const unsigned int*)(be + ko);
        const unsigned int b23 = *(const unsigned int*)(be + ko + 2);
        const unsigned int m01 = *(const unsigned int*)(ms + ko);
        const unsigned int m23 = *(const unsigned int*)(ms + ko + 2);
        float ad0 = bf2f((unsigned short)(b01 & 0xffff)) + bf2f((unsigned short)(m01 & 0xffff));
        float ad1 = bf2f((unsigned short)(b01 >> 16))    + bf2f((unsigned short)(m01 >> 16));
        float ad2 = bf2f((unsigned short)(b23 & 0xffff)) + bf2f((unsigned short)(m23 & 0xffff));
        float ad3 = bf2f((unsigned short)(b23 >> 16))    + bf2f((unsigned short)(m23 >> 16));
        float v0 = S[mt][0] + ad0, v1 = S[mt][1] + ad1;
        float v2 = S[mt][2] + ad2, v3 = S[mt][3] + ad3;
        if (kc0 + 0 >= 49) v0 = -3e30f;
        if (kc0 + 1 >= 49) v1 = -3e30f;
        if (kc0 + 2 >= 49) v2 = -3e30f;
        if (kc0 + 3 >= 49) v3 = -3e30f;
        p[mt * 4 + 0] = v0; p[mt * 4 + 1] = v1;
        p[mt * 4 + 2] = v2; p[mt * 4 + 3] = v3;
        vmax = fmaxf(fmaxf(fmaxf(v0, v1), fmaxf(v2, v3)), vmax);
      }
      vmax = fmaxf(vmax, __shfl_xor(vmax, 16, 64));
      vmax = fmaxf(vmax, __shfl_xor(vmax, 32, 64));
      float ssum = 0.f;
#pragma unroll
      for (int i = 0; i < 16; ++i) { p[i] = __expf(p[i] - vmax); ssum += p[i]; }
      ssum += __shfl_xor(ssum, 16, 64);
      ssum += __shfl_xor(ssum, 32, 64);
      const float rs = 1.f / ssum;
      unsigned int plo[4], phi[4];
#pragma unroll
      for (int mt = 0; mt < 4; ++mt) {
        plo[mt] = cvtpk(p[mt * 4 + 0], p[mt * 4 + 1]);
        phi[mt] = cvtpk(p[mt * 4 + 2], p[mt * 4 + 3]);
      }
      union { bf16x8 v; unsigned int u[4]; } PB[2];
      const int src0 = l15 + ((lg & 1) << 5);
      const int src1 = src0 + 16;
      const int sel = lg >> 1;
#pragma unroll
      for (int ks = 0; ks < 2; ++ks) {
        const int a0 = __shfl((int)plo[2 * ks], src0, 64), a1 = __shfl((int)plo[2 * ks + 1], src0, 64);
        const int b0 = __shfl((int)phi[2 * ks], src0, 64), b1 = __shfl((int)phi[2 * ks + 1], src0, 64);
        const int c0 = __shfl((int)plo[2 * ks], src1, 64), c1 = __shfl((int)plo[2 * ks + 1], src1, 64);
        const int d0 = __shfl((int)phi[2 * ks], src1, 64), d1 = __shfl((int)phi[2 * ks + 1], src1, 64);
        PB[ks].u[0] = (unsigned)(sel ? a1 : a0);
        PB[ks].u[1] = (unsigned)(sel ? b1 : b0);
        PB[ks].u[2] = (unsigned)(sel ? c1 : c0);
        PB[ks].u[3] = (unsigned)(sel ? d1 : d0);
      }
#pragma unroll
      for (int dt = 0; dt < 2; ++dt) {
        f32x4 a = {0.f, 0.f, 0.f, 0.f};
#pragma unroll
        for (int ks = 0; ks < 2; ++ks) {
          bf16x8 Vf = *(const bf16x8*)(Vt + hh * 2304 + (dt * 16 + l15) * 72 + ks * 32 + lg * 8);
          a = __builtin_amdgcn_mfma_f32_16x16x32_bf16(Vf, PB[ks].v, a, 0, 0, 0);
        }
        const unsigned int lo = cvtpk(a[0] * rs, a[1] * rs);
        const unsigned int hi = cvtpk(a[2] * rs, a[3] * rs);
        switch (g) {
          case 0: opk[0][hh][dt][0] = lo; opk[0][hh][dt][1] = hi; break;
          case 1: opk[1][hh][dt][0] = lo; opk[1][hh][dt][1] = hi; break;
          case 2: opk[2][hh][dt][0] = lo; opk[2][hh][dt][1] = hi; break;
          case 3: opk[3][hh][dt][0] = lo; opk[3][hh][dt][1] = hi; break;
          case 4: opk[4][hh][dt][0] = lo; opk[4][hh][dt][1] = hi; break;
          default: opk[5][hh][dt][0] = lo; opk[5][hh][dt][1] = hi; break;
        }
      }
    }
    __syncthreads();
  }

  // -------- dump O^T register frags into Os (aliases dead Xs) --------
  if (q < 49) {
#pragma unroll
    for (int gg = 0; gg < 6; ++gg)
#pragma unroll
      for (int hh = 0; hh < 2; ++hh)
#pragma unroll
        for (int dt = 0; dt < 2; ++dt) {
          u32x2 pk; pk[0] = opk[gg][hh][dt][0]; pk[1] = opk[gg][hh][dt][1];
          *(u32x2*)(Os + q * 392 + (2 * gg + hh) * 32 + dt * 16 + lg * 4) = pk;
        }
  }
  __syncthreads();

  // -------- GEMM2: (3 co-tiles x 4 m-tiles) register block, 2 passes --------
  {
    float* ob = out + (size_t)b * 18816;
#pragma unroll
    for (int pp = 0; pp < 2; ++pp) {
      const unsigned short* bp[3];
      float pb[3];
      int co[3];
#pragma unroll
      for (int i = 0; i < 3; ++i) {
        co[i] = (6 * w + 3 * pp + i) * 16 + l15;
        bp[i] = wsPW + co[i] * 384 + lg * 8;
        pb[i] = proj_b[co[i]];
      }
      f32x4 acc[3][4];
#pragma unroll
      for (int i = 0; i < 3; ++i)
#pragma unroll
        for (int mi = 0; mi < 4; ++mi) acc[i][mi] = (f32x4){0.f, 0.f, 0.f, 0.f};
#pragma unroll
      for (int kk = 0; kk < 12; ++kk) {
        bf16x8 A4[4];
#pragma unroll
        for (int mi = 0; mi < 4; ++mi) {
          const int ar = mi * 16 + l15;
          A4[mi] = *(const bf16x8*)(Os + (ar > 48 ? 48 : ar) * 392 + kk * 32 + lg * 8);
        }
        bf16x8 B3[3];
#pragma unroll
        for (int i = 0; i < 3; ++i) B3[i] = *(const bf16x8*)(bp[i] + kk * 32);
#pragma unroll
        for (int i = 0; i < 3; ++i)
#pragma unroll
          for (int mi = 0; mi < 4; ++mi)
            acc[i][mi] = __builtin_amdgcn_mfma_f32_16x16x32_bf16(A4[mi], B3[i], acc[i][mi], 0, 0, 0);
      }
#pragma unroll
      for (int i = 0; i < 3; ++i)
#pragma unroll
        for (int mi = 0; mi < 4; ++mi)
#pragma unroll
          for (int j = 0; j < 4; ++j) {
            const int row = mi * 16 + lg * 4 + j;
            if (row < 49) ob[row * 384 + co[i]] = acc[i][mi][j] + pb[i];
          }
    }
  }
}

// ---------------- fallback (round-2 monolith, f32-direct, known-good) ----------------
#define FXS 0
#define FQS (FXS + 64*392)
#define FKS (FQS + 2*64*40)
#define FVT (FKS + 2*64*40)
#define FPS (FVT + 2*32*72)
#define FOS (FPS + 2*64*72)
#define FMS (FOS + 64*392)
#define FBS (FMS + 2408)
#define FLDS_EL (FBS + 2028)
#define FLDS_BYTES (FLDS_EL * 2)

static __device__ __forceinline__ bf16x8 cvt8(const float* p) {
  f32x4 a = *(const f32x4*)p;
  f32x4 b = *(const f32x4*)(p + 4);
  bf16x8 r;
  r[0]=(short)f2bf(a[0]); r[1]=(short)f2bf(a[1]); r[2]=(short)f2bf(a[2]); r[3]=(short)f2bf(a[3]);
  r[4]=(short)f2bf(b[0]); r[5]=(short)f2bf(b[1]); r[6]=(short)f2bf(b[2]); r[7]=(short)f2bf(b[3]);
  return r;
}

__global__ __launch_bounds__(512, 2)
void winattn_fb(const float* __restrict__ x, const float* __restrict__ mask,
                const float* __restrict__ bias_t, const float* __restrict__ qkv_w,
                const float* __restrict__ qkv_b, const float* __restrict__ proj_w,
                const float* __restrict__ proj_b, float* __restrict__ out)
{
  extern __shared__ unsigned short sm[];
  unsigned short* Xs = sm + FXS; unsigned short* Qs = sm + FQS;
  unsigned short* Ks = sm + FKS; unsigned short* Vt = sm + FVT;
  unsigned short* Ps = sm + FPS; unsigned short* Os = sm + FOS;
  unsigned short* Ms = sm + FMS; unsigned short* Bs = sm + FBS;
  const int b = blockIdx.x, tid = threadIdx.x;
  const int w = tid >> 6, lane = tid & 63, l15 = lane & 15, lg = lane >> 4;
  const float* xw = x + b * 18816;
  for (int e = tid; e < 4704; e += 512) {
    const int f = e << 2; const int r = f / 384; const int c = f - r * 384;
    f32x4 v = *(const f32x4*)(xw + f);
    unsigned short* dst = Xs + r * 392 + c;
    dst[0]=f2bf(v[0]); dst[1]=f2bf(v[1]); dst[2]=f2bf(v[2]); dst[3]=f2bf(v[3]);
  }
  { bf16x8 z = {0,0,0,0,0,0,0,0};
    for (int e = tid; e < 735; e += 512) *(bf16x8*)(Xs + 19208 + (e << 3)) = z; }
  { const float* mw = mask + (b & 63) * 2401;
    for (int e = tid; e < 2401; e += 512) Ms[e] = f2bf(mw[e]);
    for (int e = tid; e < 2028; e += 512) Bs[e] = f2bf(bias_t[e]); }
  __syncthreads();
  for (int g = 0; g < 6; ++g) {
    int t = 6 * w; const int tEnd = t + 6;
    while (t < tEnd) {
      const int nt = t >> 2; const int hh = nt / 6; const int ntl = nt - hh * 6;
      const int s = ntl >> 1; const int dd = ((nt & 1) << 4) + l15;
      const int o = s * 384 + (2 * g + hh) * 32 + dd;
      bf16x8 Bf[12];
      const float* wp = qkv_w + o * 384 + lg * 8;
#pragma unroll
      for (int kk = 0; kk < 12; ++kk) Bf[kk] = cvt8(wp + kk * 32);
      const float biasc = qkv_b[o];
      for (; t < tEnd && (t >> 2) == nt; ++t) {
        const int mt = t & 3;
        f32x4 acc = {0.f,0.f,0.f,0.f};
        const unsigned short* ap = Xs + (mt * 16 + l15) * 392 + lg * 8;
#pragma unroll
        for (int kk = 0; kk < 12; ++kk) {
          bf16x8 Af = *(const bf16x8*)(ap + kk * 32);
          acc = __builtin_amdgcn_mfma_f32_16x16x32_bf16(Af, Bf[kk], acc, 0,0,0);
        }
#pragma unroll
        for (int j = 0; j < 4; ++j) {
          const int row = mt * 16 + lg * 4 + j;
          const unsigned short hv = f2bf(acc[j] + biasc);
          if (s == 0) Qs[hh * 2560 + row * 40 + dd] = hv;
          else if (s == 1) Ks[hh * 2560 + row * 40 + dd] = hv;
          else Vt[hh * 2304 + dd * 72 + row] = hv;
        }
      }
    }
    __syncthreads();
    {
      const int hh = w >> 2; const int mt = w & 3; const int head = 2 * g + hh;
      bf16x8 Aq = *(const bf16x8*)(Qs + hh * 2560 + (mt * 16 + l15) * 40 + lg * 8);
      f32x4 accs[4];
#pragma unroll
      for (int nt = 0; nt < 4; ++nt) {
        bf16x8 Bk = *(const bf16x8*)(Ks + hh * 2560 + (nt * 16 + l15) * 40 + lg * 8);
        f32x4 z = {0.f,0.f,0.f,0.f};
        accs[nt] = __builtin_amdgcn_mfma_f32_16x16x32_bf16(Aq, Bk, z, 0,0,0);
      }
#pragma unroll
      for (int j = 0; j < 4; ++j) {
        const int row = mt * 16 + lg * 4 + j;
        float sv[4]; float vmax = -3e30f;
#pragma unroll
        for (int nt = 0; nt < 4; ++nt) {
          const int col = nt * 16 + l15;
          float v = accs[nt][j] * NSCALE;
          if (col < 49) { if (row < 49) {
              const int i1 = row / 7, j1 = row - i1 * 7;
              const int i2 = col / 7, j2 = col - i2 * 7;
              const int ridx = (i1 - i2 + 6) * 13 + (j1 - j2 + 6);
              v += bf2f(Ms[row * 49 + col]) + bf2f(Bs[ridx * 12 + head]); } }
          else v = -3e30f;
          sv[nt] = v; vmax = fmaxf(vmax, v);
        }
#pragma unroll
        for (int mm = 1; mm < 16; mm <<= 1) vmax = fmaxf(vmax, __shfl_xor(vmax, mm, 64));
        float ssum = 0.f;
#pragma unroll
        for (int nt = 0; nt < 4; ++nt) { sv[nt] = __expf(sv[nt] - vmax); ssum += sv[nt]; }
#pragma unroll
        for (int mm = 1; mm < 16; mm <<= 1) ssum += __shfl_xor(ssum, mm, 64);
        const float rs = 1.f / ssum;
#pragma unroll
        for (int nt = 0; nt < 4; ++nt)
          Ps[hh * 4608 + row * 72 + nt * 16 + l15] = f2bf(sv[nt] * rs);
      }
    }
    __syncthreads();
    {
      const int hh = w >> 2; const int mt = w & 3; const int head = 2 * g + hh;
#pragma unroll
      for (int nt = 0; nt < 2; ++nt) {
        f32x4 acc = {0.f,0.f,0.f,0.f};
#pragma unroll
        for (int kk = 0; kk < 2; ++kk) {
          bf16x8 Ap = *(const bf16x8*)(Ps + hh * 4608 + (mt * 16 + l15) * 72 + kk * 32 + lg * 8);
          bf16x8 Bv = *(const bf16x8*)(Vt + hh * 2304 + (nt * 16 + l15) * 72 + kk * 32 + lg * 8);
          acc = __builtin_amdgcn_mfma_f32_16x16x32_bf16(Ap, Bv, acc, 0,0,0);
        }
#pragma unroll
        for (int j = 0; j < 4; ++j)
          Os[(mt * 16 + lg * 4 + j) * 392 + head * 32 + nt * 16 + l15] = f2bf(acc[j]);
      }
    }
    __syncthreads();
  }
  for (int nt = 3 * w; nt < 3 * w + 3; ++nt) {
    const int co = nt * 16 + l15;
    bf16x8 Bf[12];
    const float* wp = proj_w + co * 384 + lg * 8;
#pragma unroll
    for (int kk = 0; kk < 12; ++kk) Bf[kk] = cvt8(wp + kk * 32);
    const float pb = proj_b[co];
#pragma unroll
    for (int mt = 0; mt < 4; ++mt) {
      f32x4 acc = {0.f,0.f,0.f,0.f};
      const unsigned short* ap = Os + (mt * 16 + l15) * 392 + lg * 8;
#pragma unroll
      for (int kk = 0; kk < 12; ++kk) {
        bf16x8 Af = *(const bf16x8*)(ap + kk * 32);
        acc = __builtin_amdgcn_mfma_f32_16x16x32_bf16(Af, Bf[kk], acc, 0,0,0);
      }
#pragma unroll
      for (int j = 0; j < 4; ++j) {
        const int row = mt * 16 + lg * 4 + j;
        if (row < 49) out[b * 18816 + row * 384 + co] = acc[j] + pb;
      }
    }
  }
}

extern "C" void kernel_launch(void* const* d_in, const int* in_sizes, int n_in,
                              void* d_out, int out_size, void* d_ws, size_t ws_size,
                              hipStream_t stream) {
  const float* x      = (const float*)d_in[0];
  const float* mask   = (const float*)d_in[1];
  const float* bias_t = (const float*)d_in[2];
  const float* qkv_w  = (const float*)d_in[3];
  const float* qkv_b  = (const float*)d_in[4];
  const float* proj_w = (const float*)d_in[5];
  const float* proj_b = (const float*)d_in[6];
  float* out = (float*)d_out;

  if (ws_size >= (size_t)W_BYTES) {
    unsigned short* ws = (unsigned short*)d_ws;
    cvt_w_kernel<<<dim3(1024), dim3(256), 0, stream>>>(qkv_w, proj_w, ws);
    biase_kernel<<<dim3(12), dim3(256), 0, stream>>>(bias_t, ws);
    (void)hipFuncSetAttribute((const void*)winattn14,
                              hipFuncAttributeMaxDynamicSharedMemorySize, LDS_BYTES2);
    winattn14<<<dim3(4096), dim3(256), LDS_BYTES2, stream>>>(
        x, mask, qkv_b, proj_b, ws, out);
  } else {
    (void)hipFuncSetAttribute((const void*)winattn_fb,
                              hipFuncAttributeMaxDynamicSharedMemorySize, FLDS_BYTES);
    winattn_fb<<<dim3(4096), dim3(512), FLDS_BYTES, stream>>>(
        x, mask, bias_t, qkv_w, qkv_b, proj_w, proj_b, out);
  }
}